// Round 3
// baseline (537.455 us; speedup 1.0000x reference)
//
#include <hip/hip_runtime.h>
#include <hip/hip_bf16.h>

#define BB 32
#define CC 64
#define HH 128
#define WW 128
#define OO 64
#define KK 4
#define HIDDEN 17
#define HW (HH*WW)

typedef __attribute__((ext_vector_type(8)))  short bf16x8;
typedef __attribute__((ext_vector_type(16))) float f32x16;

__device__ __forceinline__ unsigned short f2bf(float f) {
    unsigned u = __float_as_uint(f);
    unsigned r = (u + 0x7FFFu + ((u >> 16) & 1u)) >> 16;   // RNE
    return (unsigned short)r;
}

// ---------------- zero scratch (pooled) ----------------
__global__ __launch_bounds__(256) void zero_kernel(float* __restrict__ p, int n) {
    int i = blockIdx.x * 256 + threadIdx.x;
    if (i < n) p[i] = 0.f;
}

// ---------------- Kernel 1 (fallback only): avg pool ----------------
__global__ __launch_bounds__(256) void pool_kernel(const float* __restrict__ x,
                                                   float* __restrict__ pooled) {
    int bc = blockIdx.x;
    const float* p = x + (size_t)bc * HW;
    float s = 0.f;
    for (int i = threadIdx.x; i < HW; i += 256) s += p[i];
    #pragma unroll
    for (int off = 32; off > 0; off >>= 1) s += __shfl_down(s, off, 64);
    __shared__ float warp_s[4];
    int lane = threadIdx.x & 63, wv = threadIdx.x >> 6;
    if (lane == 0) warp_s[wv] = s;
    __syncthreads();
    if (threadIdx.x == 0) {
        float t = warp_s[0] + warp_s[1] + warp_s[2] + warp_s[3];
        pooled[bc] = t * (1.f / (float)HW);
    }
}

// ---------------- Kernel 2: MLP -> softmax -> attn, agg_b (1 wave per sample) ----------------
__global__ __launch_bounds__(64) void attn_kernel(const float* __restrict__ pooled,
                                                  const float* __restrict__ fc1_w,
                                                  const float* __restrict__ fc2_w,
                                                  const float* __restrict__ fc2_b,
                                                  const float* __restrict__ scale,
                                                  const float* __restrict__ bias,
                                                  float* __restrict__ attn,
                                                  float* __restrict__ agg_b) {
    const int b = blockIdx.x;
    const int lane = threadIdx.x;
    float pv = pooled[b * CC + lane];
    float h[HIDDEN];
    #pragma unroll
    for (int i = 0; i < HIDDEN; ++i) {
        float s = pv * fc1_w[i * CC + lane];
        #pragma unroll
        for (int off = 32; off > 0; off >>= 1) s += __shfl_xor(s, off, 64);
        h[i] = fmaxf(s, 0.f);           // uniform across lanes
    }
    float sc = scale[0];
    float logits[KK];
    #pragma unroll
    for (int k = 0; k < KK; ++k) {
        float s = fc2_b[k];
        #pragma unroll
        for (int j = 0; j < HIDDEN; ++j) s += h[j] * fc2_w[k * (HIDDEN + 2) + j];
        s += sc * (fc2_w[k * (HIDDEN + 2) + HIDDEN] + fc2_w[k * (HIDDEN + 2) + HIDDEN + 1]);
        logits[k] = s;
    }
    float m = fmaxf(fmaxf(logits[0], logits[1]), fmaxf(logits[2], logits[3]));
    float e[KK], tot = 0.f;
    #pragma unroll
    for (int k = 0; k < KK; ++k) { e[k] = __expf(logits[k] - m); tot += e[k]; }
    float inv = 1.f / tot;
    float a[KK];
    #pragma unroll
    for (int k = 0; k < KK; ++k) a[k] = e[k] * inv;
    if (lane < KK) attn[b * KK + lane] = a[lane];
    float s = 0.f;
    #pragma unroll
    for (int k = 0; k < KK; ++k) s += a[k] * bias[k * OO + lane];
    agg_b[b * OO + lane] = s;
}

// ---------------- Kernel 3a: mix weights -> bf16 [b][j9][o][c] ----------------
__global__ __launch_bounds__(256) void aggw_bf_kernel(const float* __restrict__ attn,
                                                      const float* __restrict__ weight,
                                                      unsigned int* __restrict__ wbf) {
    int idx = blockIdx.x * 256 + threadIdx.x;
    const int total = BB * 9 * OO * (CC / 2);
    if (idx >= total) return;
    int cp = idx & 31;
    int t  = idx >> 5;
    int o  = t & 63;
    int t2 = t >> 6;
    int j  = t2 % 9;
    int b  = t2 / 9;
    float a0 = attn[b * KK + 0], a1 = attn[b * KK + 1],
          a2 = attn[b * KK + 2], a3 = attn[b * KK + 3];
    int c0 = cp * 2;
    float s0 = a0 * weight[((0 * OO + o) * CC + c0) * 9 + j]
             + a1 * weight[((1 * OO + o) * CC + c0) * 9 + j]
             + a2 * weight[((2 * OO + o) * CC + c0) * 9 + j]
             + a3 * weight[((3 * OO + o) * CC + c0) * 9 + j];
    float s1 = a0 * weight[((0 * OO + o) * CC + c0 + 1) * 9 + j]
             + a1 * weight[((1 * OO + o) * CC + c0 + 1) * 9 + j]
             + a2 * weight[((2 * OO + o) * CC + c0 + 1) * 9 + j]
             + a3 * weight[((3 * OO + o) * CC + c0 + 1) * 9 + j];
    wbf[idx] = (unsigned int)f2bf(s0) | ((unsigned int)f2bf(s1) << 16);
}

// ---------------- Kernel 3b: zero padded borders of x_bf ----------------
__global__ __launch_bounds__(256) void border_kernel(unsigned int* __restrict__ xbf32) {
    int yp = blockIdx.x;
    int b  = blockIdx.y;
    unsigned int* row = xbf32 + ((size_t)b * 130 + yp) * 130 * 32;
    if (yp == 0 || yp == 129) {
        for (int i = threadIdx.x; i < 130 * 32; i += 256) row[i] = 0u;
    } else {
        if (threadIdx.x < 32) row[threadIdx.x] = 0u;
        else if (threadIdx.x >= 64 && threadIdx.x < 96)
            row[129 * 32 + (threadIdx.x - 64)] = 0u;
    }
}

// ---------------- Kernel 3c: transpose + fused pool ----------------
__global__ __launch_bounds__(256) void xpose_pool_kernel(const float* __restrict__ x,
                                                         unsigned int* __restrict__ xbf32,
                                                         float* __restrict__ pooled) {
    __shared__ float t[64][65];
    const int y  = blockIdx.x;
    const int b  = blockIdx.y;
    const int x0 = blockIdx.z * 64;
    const int tid = threadIdx.x;
    const int xl = tid & 63;
    const int cs = tid >> 6;
    float v[16];
    #pragma unroll
    for (int cc = 0; cc < 16; ++cc) {
        int c = cc * 4 + cs;
        v[cc] = x[((size_t)(b * CC + c) * HH + y) * WW + x0 + xl];
        t[c][xl] = v[cc];
    }
    // fused pool: wave-reduce each channel's 64-x partial
    #pragma unroll
    for (int cc = 0; cc < 16; ++cc) {
        float s = v[cc];
        #pragma unroll
        for (int off = 32; off > 0; off >>= 1) s += __shfl_down(s, off, 64);
        if (xl == 0) atomicAdd(&pooled[b * CC + cc * 4 + cs], s * (1.f / (float)HW));
    }
    __syncthreads();
    {
        const int cp = tid & 31;
        const int xs = tid >> 5;
        const int c0 = cp * 2;
        #pragma unroll
        for (int xx = 0; xx < 8; ++xx) {
            int xl2 = xx * 8 + xs;
            unsigned int pack = (unsigned int)f2bf(t[c0][xl2]) |
                                ((unsigned int)f2bf(t[c0 + 1][xl2]) << 16);
            xbf32[(((size_t)b * 130 + (y + 1)) * 130 + (x0 + xl2 + 1)) * 32 + cp] = pack;
        }
    }
}

// ---------------- Kernel 4: implicit-GEMM conv, software-pipelined ----------------
// grid (64 y-pairs, 32 b), block 256 = 4 waves.
// wave w: y = y0 + (w>>1), x0 = (w&1)*64. Each wave: full M=64 (2 o-tiles) x N=64 (2 n-tiles).
__global__ __launch_bounds__(256) void conv_mfma_kernel(const short* __restrict__ xbf,
                                                        const short* __restrict__ wbf,
                                                        const float* __restrict__ agg_b,
                                                        float* __restrict__ out) {
    const int b    = blockIdx.y;
    const int tid  = threadIdx.x;
    const int wv   = tid >> 6;
    const int lane = tid & 63;
    const int m    = lane & 31;
    const int kh2  = lane >> 5;
    const int y    = blockIdx.x * 2 + (wv >> 1);
    const int x0   = (wv & 1) * 64;

    f32x16 acc00 = {}, acc01 = {}, acc10 = {}, acc11 = {};  // [o-tile][n-tile]

    const short* Awave = wbf + (size_t)b * 9 * (OO * CC) + (size_t)m * CC + kh2 * 8;
    const short* Bwave = xbf + (((size_t)b * 130 + y) * 130 + x0 + m) * CC + kh2 * 8;

    bf16x8 Af[2][2][4];   // [buf][o-tile][kc]
    bf16x8 Bf[2][2][4];   // [buf][n-tile][kc]

    // prologue: stage j9 = 0 (kh=0, kw=0)
    #pragma unroll
    for (int nt = 0; nt < 2; ++nt)
        #pragma unroll
        for (int kc = 0; kc < 4; ++kc)
            Bf[0][nt][kc] = *(const bf16x8*)(Bwave + (nt * 32) * CC + kc * 16);
    #pragma unroll
    for (int t = 0; t < 2; ++t)
        #pragma unroll
        for (int kc = 0; kc < 4; ++kc)
            Af[0][t][kc] = *(const bf16x8*)(Awave + (t * 32) * CC + kc * 16);

    #pragma unroll
    for (int j9 = 0; j9 < 9; ++j9) {
        const int cur = j9 & 1, nxt = cur ^ 1;
        if (j9 < 8) {
            const int kh = (j9 + 1) / 3, kw = (j9 + 1) % 3;
            #pragma unroll
            for (int nt = 0; nt < 2; ++nt)
                #pragma unroll
                for (int kc = 0; kc < 4; ++kc)
                    Bf[nxt][nt][kc] = *(const bf16x8*)(Bwave + (kh * 130 + nt * 32 + kw) * CC + kc * 16);
            #pragma unroll
            for (int t = 0; t < 2; ++t)
                #pragma unroll
                for (int kc = 0; kc < 4; ++kc)
                    Af[nxt][t][kc] = *(const bf16x8*)(Awave + (size_t)(j9 + 1) * (OO * CC) + (t * 32) * CC + kc * 16);
        }
        #pragma unroll
        for (int kc = 0; kc < 4; ++kc) {
            acc00 = __builtin_amdgcn_mfma_f32_32x32x16_bf16(Af[cur][0][kc], Bf[cur][0][kc], acc00, 0, 0, 0);
            acc10 = __builtin_amdgcn_mfma_f32_32x32x16_bf16(Af[cur][1][kc], Bf[cur][0][kc], acc10, 0, 0, 0);
            acc01 = __builtin_amdgcn_mfma_f32_32x32x16_bf16(Af[cur][0][kc], Bf[cur][1][kc], acc01, 0, 0, 0);
            acc11 = __builtin_amdgcn_mfma_f32_32x32x16_bf16(Af[cur][1][kc], Bf[cur][1][kc], acc11, 0, 0, 0);
        }
    }

    // epilogue: row = (r&3)+8*(r>>2)+4*kh2, col = m
    #pragma unroll
    for (int r = 0; r < 16; ++r) {
        int row = (r & 3) + 8 * (r >> 2) + 4 * kh2;
        float bias0 = agg_b[b * OO + row];
        float bias1 = agg_b[b * OO + 32 + row];
        size_t base0 = ((size_t)(b * OO + row) * HH + y) * WW;
        size_t base1 = ((size_t)(b * OO + 32 + row) * HH + y) * WW;
        out[base0 + x0 + m]      = acc00[r] + bias0;
        out[base0 + x0 + 32 + m] = acc01[r] + bias0;
        out[base1 + x0 + m]      = acc10[r] + bias1;
        out[base1 + x0 + 32 + m] = acc11[r] + bias1;
    }
}

// ================= fallback fp32 path =================
__global__ __launch_bounds__(256) void aggw_kernel(const float* __restrict__ attn,
                                                   const float* __restrict__ weight,
                                                   float* __restrict__ agg_w) {
    int idx = blockIdx.x * 256 + threadIdx.x;
    const int total = BB * CC * OO * 9;
    if (idx >= total) return;
    int j  = idx % 9;
    int t  = idx / 9;
    int o  = t & 63;
    int t2 = t >> 6;
    int c  = t2 & 63;
    int b  = t2 >> 6;
    float s = 0.f;
    #pragma unroll
    for (int k = 0; k < KK; ++k)
        s += attn[b * KK + k] * weight[((k * OO + o) * CC + c) * 9 + j];
    agg_w[idx] = s;
}

__global__ __launch_bounds__(256) void conv_kernel(const float* __restrict__ x,
                                                   const float* __restrict__ agg_w,
                                                   const float* __restrict__ agg_b,
                                                   float* __restrict__ out) {
    __shared__ float s_in[2][18 * 20];
    const int tid = threadIdx.x;
    const int tx = tid & 15, ty = tid >> 4;
    const int b  = blockIdx.z;
    const int o0 = blockIdx.y * 8;
    const int sy = (blockIdx.x >> 3) * 16;
    const int sx = (blockIdx.x & 7) * 16;
    const float* __restrict__ xb = x + (size_t)b * CC * HW;
    const float* __restrict__ wb = agg_w + (size_t)b * CC * OO * 9;
    float acc[8];
    #pragma unroll
    for (int o = 0; o < 8; ++o) acc[o] = agg_b[b * OO + o0 + o];
    auto load_ch = [&](int c, float* dst) {
        for (int i = tid; i < 18 * 18; i += 256) {
            int r = i / 18, col = i - r * 18;
            int gy = sy + r - 1, gx = sx + col - 1;
            float v = 0.f;
            if (gy >= 0 && gy < HH && gx >= 0 && gx < WW) v = xb[c * HW + gy * WW + gx];
            dst[r * 20 + col] = v;
        }
    };
    load_ch(0, s_in[0]);
    __syncthreads();
    for (int c = 0; c < CC; ++c) {
        const int buf = c & 1;
        if (c + 1 < CC) load_ch(c + 1, s_in[buf ^ 1]);
        float in[3][3];
        #pragma unroll
        for (int kh = 0; kh < 3; ++kh)
            #pragma unroll
            for (int kw = 0; kw < 3; ++kw)
                in[kh][kw] = s_in[buf][(ty + kh) * 20 + (tx + kw)];
        const float* __restrict__ wc = wb + (c * OO + o0) * 9;
        #pragma unroll
        for (int o = 0; o < 8; ++o)
            #pragma unroll
            for (int kh = 0; kh < 3; ++kh)
                #pragma unroll
                for (int kw = 0; kw < 3; ++kw)
                    acc[o] += in[kh][kw] * wc[o * 9 + kh * 3 + kw];
        __syncthreads();
    }
    const int oy = sy + ty, ox = sx + tx;
    #pragma unroll
    for (int o = 0; o < 8; ++o)
        out[((size_t)(b * OO + o0 + o) * HH + oy) * WW + ox] = acc[o];
}

extern "C" void kernel_launch(void* const* d_in, const int* in_sizes, int n_in,
                              void* d_out, int out_size, void* d_ws, size_t ws_size,
                              hipStream_t stream) {
    const float* x      = (const float*)d_in[0];
    const float* scale  = (const float*)d_in[1];
    const float* fc1_w  = (const float*)d_in[2];
    const float* fc2_w  = (const float*)d_in[3];
    const float* fc2_b  = (const float*)d_in[4];
    const float* weight = (const float*)d_in[5];
    const float* bias   = (const float*)d_in[6];
    float* out = (float*)d_out;

    const size_t XBF_BYTES = (size_t)BB * 130 * 130 * CC * 2;
    const size_t WBF_BYTES = (size_t)BB * 9 * OO * CC * 2;
    const size_t NEED = XBF_BYTES + WBF_BYTES + (2048 + 128 + 2048) * 4 + 256;

    if (ws_size >= NEED) {
        short*        xbf   = (short*)d_ws;
        unsigned int* xbf32 = (unsigned int*)d_ws;
        unsigned int* wbf32 = (unsigned int*)((char*)d_ws + XBF_BYTES);
        short*        wbf   = (short*)wbf32;
        float*        fls   = (float*)((char*)d_ws + XBF_BYTES + WBF_BYTES);
        float* pooled = fls;
        float* attn   = fls + 2048;
        float* agg_b  = fls + 2048 + 128;

        zero_kernel<<<8, 256, 0, stream>>>(pooled, 2048);
        border_kernel<<<dim3(130, BB), 256, 0, stream>>>(xbf32);
        xpose_pool_kernel<<<dim3(HH, BB, 2), 256, 0, stream>>>(x, xbf32, pooled);
        attn_kernel<<<BB, 64, 0, stream>>>(pooled, fc1_w, fc2_w, fc2_b, scale, bias, attn, agg_b);
        const int aggw_total = BB * 9 * OO * (CC / 2);
        aggw_bf_kernel<<<(aggw_total + 255) / 256, 256, 0, stream>>>(attn, weight, wbf32);
        conv_mfma_kernel<<<dim3(64, BB), 256, 0, stream>>>(xbf, wbf, agg_b, out);
    } else {
        float* ws     = (float*)d_ws;
        float* attn   = ws;
        float* agg_b  = ws + 128;
        float* pooled = ws + 128 + 2048;
        float* agg_w  = ws + 128 + 2048 + 2048;
        pool_kernel<<<BB * CC, 256, 0, stream>>>(x, pooled);
        attn_kernel<<<BB, 64, 0, stream>>>(pooled, fc1_w, fc2_w, fc2_b, scale, bias, attn, agg_b);
        const int aggw_total = BB * CC * OO * 9;
        aggw_kernel<<<(aggw_total + 255) / 256, 256, 0, stream>>>(attn, weight, agg_w);
        conv_kernel<<<dim3(64, 8, BB), 256, 0, stream>>>(x, agg_w, agg_b, out);
    }
}